// Round 5
// baseline (200.901 us; speedup 1.0000x reference)
//
#include <hip/hip_runtime.h>
#include <hip/hip_bf16.h>

#define B_SZ 8
#define LSEQ 200
#define DMODEL 256
#define DINNER 512
#define DSTATE 64
#define DTRANK 16
#define ROWS (B_SZ * LSEQ)   // 1600

using bf16x8 = __attribute__((ext_vector_type(8))) short;
using f32x4  = __attribute__((ext_vector_type(4))) float;

__device__ __forceinline__ float softplusf(float x) {
    return (x > 20.f) ? x : log1pf(__expf(x));
}
__device__ __forceinline__ float siluf(float x) {
    return x / (1.f + __expf(-x));
}
__device__ __forceinline__ unsigned short f2bf(float f) {
    union { float f; unsigned int u; } v; v.f = f;
    unsigned int r = v.u + 0x7FFF + ((v.u >> 16) & 1);   // RNE
    return (unsigned short)(r >> 16);
}
__device__ __forceinline__ float bf2f(unsigned short u) {
    union { unsigned int i; float f; } v;
    v.i = ((unsigned int)u) << 16;
    return v.f;
}
// 8-way mux by 3-bit divergent selector (7 cndmask)
__device__ __forceinline__ float mux8(const float* v, int s) {
    float a = (s & 1) ? v[1] : v[0];
    float b = (s & 1) ? v[3] : v[2];
    float c = (s & 1) ? v[5] : v[4];
    float d = (s & 1) ? v[7] : v[6];
    float e = (s & 2) ? b : a;
    float f = (s & 2) ? d : c;
    return (s & 4) ? f : e;
}

// ---------------------------------------------------------------------------
// One-time prep: split x into bf16 hi/lo; transpose+split W_in, W_x, W_out
// into [N][K] k-contiguous bf16 hi/lo (B-operand layout for MFMA).
// ---------------------------------------------------------------------------
__global__ __launch_bounds__(256) void prep_w_k(
    const float* __restrict__ x, const float* __restrict__ W_in,
    const float* __restrict__ W_x, const float* __restrict__ W_out,
    unsigned short* __restrict__ x_hi,  unsigned short* __restrict__ x_lo,
    unsigned short* __restrict__ WiT_hi, unsigned short* __restrict__ WiT_lo,
    unsigned short* __restrict__ WxT_hi, unsigned short* __restrict__ WxT_lo,
    unsigned short* __restrict__ WoT_hi, unsigned short* __restrict__ WoT_lo)
{
    int idx = blockIdx.x * 256 + threadIdx.x;
    float v;
    unsigned short *dh, *dl;
    size_t di;
    if (idx < 409600) {                       // x: straight split (k-contig already)
        v = x[idx]; dh = x_hi; dl = x_lo; di = idx;
    } else if (idx < 409600 + 262144) {       // W_in [256][1024] -> WiT [1024][256]
        int l = idx - 409600;
        int n = l >> 8, k = l & 255;
        v = W_in[(size_t)k * 1024 + n]; dh = WiT_hi; dl = WiT_lo; di = l;
    } else if (idx < 409600 + 262144 + 73728) { // W_x [512][144] -> WxT [144][512]
        int l = idx - (409600 + 262144);
        int n = l >> 9, k = l & 511;
        v = W_x[(size_t)k * 144 + n]; dh = WxT_hi; dl = WxT_lo; di = l;
    } else if (idx < 409600 + 262144 + 73728 + 131072) { // W_out [512][256] -> WoT [256][512]
        int l = idx - (409600 + 262144 + 73728);
        int n = l >> 9, k = l & 511;
        v = W_out[(size_t)k * 256 + n]; dh = WoT_hi; dl = WoT_lo; di = l;
    } else return;
    unsigned short h = f2bf(v);
    dh[di] = h;
    dl[di] = f2bf(v - bf2f(h));
}

// ---------------------------------------------------------------------------
// Split-bf16 MFMA GEMM: hi·hi + hi·lo + lo·hi. 64x64 tile, 4 waves of 32x32.
// ---------------------------------------------------------------------------
__global__ __launch_bounds__(256) void gemm_mfma(
    const unsigned short* __restrict__ A_hi, const unsigned short* __restrict__ A_lo,
    const unsigned short* __restrict__ BT_hi, const unsigned short* __restrict__ BT_lo,
    float* __restrict__ C, int M, int N, int K, const float* __restrict__ resid)
{
    __shared__ unsigned short As_hi[64 * 40], As_lo[64 * 40];
    __shared__ unsigned short Bs_hi[64 * 40], Bs_lo[64 * 40];

    const int t    = threadIdx.x;
    const int m0   = blockIdx.y * 64;
    const int n0   = blockIdx.x * 64;
    const int lane = t & 63;
    const int w    = t >> 6;
    const int wm   = (w >> 1) * 32;
    const int wn   = (w & 1) * 32;
    const int fr   = lane & 15;
    const int fq   = lane >> 4;

    const int sr = t >> 2;
    const int sc = (t & 3) * 8;

    f32x4 acc[2][2] = {};

    const size_t a_off = (size_t)(m0 + sr) * K + sc;
    const int    brow  = n0 + sr;
    const size_t b_off = (size_t)brow * K + sc;
    const bool   bok   = brow < N;

    for (int k0 = 0; k0 < K; k0 += 32) {
        int4 ah = *(const int4*)(A_hi + a_off + k0);
        int4 al = *(const int4*)(A_lo + a_off + k0);
        int4 bh = make_int4(0, 0, 0, 0), bl = make_int4(0, 0, 0, 0);
        if (bok) {
            bh = *(const int4*)(BT_hi + b_off + k0);
            bl = *(const int4*)(BT_lo + b_off + k0);
        }
        __syncthreads();
        *(int4*)&As_hi[sr * 40 + sc] = ah;
        *(int4*)&As_lo[sr * 40 + sc] = al;
        *(int4*)&Bs_hi[sr * 40 + sc] = bh;
        *(int4*)&Bs_lo[sr * 40 + sc] = bl;
        __syncthreads();

        bf16x8 a_h[2], a_l[2], b_h[2], b_l[2];
#pragma unroll
        for (int mi = 0; mi < 2; mi++) {
            int row = wm + mi * 16 + fr;
            a_h[mi] = *(const bf16x8*)&As_hi[row * 40 + fq * 8];
            a_l[mi] = *(const bf16x8*)&As_lo[row * 40 + fq * 8];
        }
#pragma unroll
        for (int ni = 0; ni < 2; ni++) {
            int row = wn + ni * 16 + fr;
            b_h[ni] = *(const bf16x8*)&Bs_hi[row * 40 + fq * 8];
            b_l[ni] = *(const bf16x8*)&Bs_lo[row * 40 + fq * 8];
        }
#pragma unroll
        for (int mi = 0; mi < 2; mi++)
#pragma unroll
            for (int ni = 0; ni < 2; ni++) {
                acc[mi][ni] = __builtin_amdgcn_mfma_f32_16x16x32_bf16(a_h[mi], b_h[ni], acc[mi][ni], 0, 0, 0);
                acc[mi][ni] = __builtin_amdgcn_mfma_f32_16x16x32_bf16(a_h[mi], b_l[ni], acc[mi][ni], 0, 0, 0);
                acc[mi][ni] = __builtin_amdgcn_mfma_f32_16x16x32_bf16(a_l[mi], b_h[ni], acc[mi][ni], 0, 0, 0);
            }
    }

#pragma unroll
    for (int mi = 0; mi < 2; mi++)
#pragma unroll
        for (int ni = 0; ni < 2; ni++) {
            int col = n0 + wn + ni * 16 + fr;
            if (col < N) {
#pragma unroll
                for (int reg = 0; reg < 4; reg++) {
                    int row = m0 + wm + mi * 16 + fq * 4 + reg;
                    float v = acc[mi][ni][reg];
                    if (resid) v += resid[(size_t)row * N + col];
                    C[(size_t)row * N + col] = v;
                }
            }
        }
}

// ---------------------------------------------------------------------------
// Depthwise causal conv (width 4) + bias + silu; emits fp32 + split bf16.
// ---------------------------------------------------------------------------
__global__ __launch_bounds__(256) void conv_silu_k(
    const float* __restrict__ xz, const float* __restrict__ conv_w,
    const float* __restrict__ conv_b, float* __restrict__ xm,
    unsigned short* __restrict__ xm_hi, unsigned short* __restrict__ xm_lo)
{
    int idx = blockIdx.x * 256 + threadIdx.x;   // < ROWS*512 = 819200
    int c = idx & 511;
    int r = idx >> 9;
    int l = r % LSEQ;

    float w0 = conv_w[c * 4 + 0];
    float w1 = conv_w[c * 4 + 1];
    float w2 = conv_w[c * 4 + 2];
    float w3 = conv_w[c * 4 + 3];

    const float* base = xz + (size_t)r * 1024 + c;
    float acc = conv_b[c];
    if (l >= 3) acc = fmaf(base[-3 * 1024], w0, acc);
    if (l >= 2) acc = fmaf(base[-2 * 1024], w1, acc);
    if (l >= 1) acc = fmaf(base[-1 * 1024], w2, acc);
    acc = fmaf(base[0], w3, acc);

    float s = siluf(acc);
    xm[idx] = s;
    unsigned short h = f2bf(s);
    xm_hi[idx] = h;
    xm_lo[idx] = f2bf(s - bf2f(h));
}

// ---------------------------------------------------------------------------
// Pack B and C (with phase modulation) into lane-contiguous 8-step tiles:
// bcq[b][lblk][n][t][2]  (lblk = l>>3, t = l&7)
// ---------------------------------------------------------------------------
__global__ __launch_bounds__(256) void pack_bc_k(
    const float* __restrict__ cosp, const float* __restrict__ sinp,
    const float* __restrict__ W_phase, const float* __restrict__ xp,
    float* __restrict__ bcq)
{
    int idx = blockIdx.x * 256 + threadIdx.x;   // < ROWS*64 = 102400
    int n = idx & 63;
    int r = idx >> 6;
    int b = r / LSEQ, l = r % LSEQ;

    float acc = 0.f;
#pragma unroll
    for (int j = 0; j < 4; j++) {
        float cp = cosp[(b * 4 + j) * LSEQ + l];
        float sp = sinp[(b * 4 + j) * LSEQ + l];
        acc = fmaf(cp, W_phase[j * 64 + n], acc);
        acc = fmaf(sp, W_phase[(4 + j) * 64 + n], acc);
    }
    float Bv = xp[(size_t)r * 144 + 16 + n];
    float Cv = xp[(size_t)r * 144 + 80 + n] + acc;
    size_t o = ((((size_t)b * 25 + (l >> 3)) * 64 + n) * 8 + (l & 7)) * 2;
    *(float2*)&bcq[o] = make_float2(Bv, Cv);
}

// ---------------------------------------------------------------------------
// dtq_k: per (b, 64-d tile, 32-l tile) block computes
//   dt  = softplus(xp[:,:16]·W_dt[:,d] + b_dt[d]) * (1+softplus(mean(dmag)))
// and writes dtq[b][d][l] = (dt, dt*u, u, silu(z))   -- l-contiguous float4.
// All global reads coalesced (d-fastest), writes coalesced (l-fastest) via LDS.
// ---------------------------------------------------------------------------
__global__ __launch_bounds__(256) void dtq_k(
    const float* __restrict__ xp, const float* __restrict__ W_dt,
    const float* __restrict__ b_dt, const float* __restrict__ dmag,
    const float* __restrict__ xm, const float* __restrict__ xz,
    float4* __restrict__ dtq)
{
    const int b   = blockIdx.z;
    const int dt0 = blockIdx.y * 64;
    const int lt0 = blockIdx.x * 32;
    const int t   = threadIdx.x;

    __shared__ float Wl[16][64];
    __shared__ float xr[32][17];
    __shared__ float sc[32];
    __shared__ float xmu[32][64];
    __shared__ float xzs[32][64];

#pragma unroll
    for (int e = 0; e < 4; e++) {
        int idx = t + 256 * e;             // 0..1023
        int i = idx >> 6, j = idx & 63;
        Wl[i][j] = W_dt[i * 512 + dt0 + j];
    }
#pragma unroll
    for (int e = 0; e < 2; e++) {
        int idx = t + 256 * e;             // 0..511
        int ll = idx >> 4, i = idx & 15;
        int l = lt0 + ll;
        xr[ll][i] = (l < LSEQ) ? xp[((size_t)(b * LSEQ + l)) * 144 + i] : 0.f;
    }
    if (t < 32) {
        int l = lt0 + t;
        float dm = 0.f;
        if (l < LSEQ) {
#pragma unroll
            for (int j = 0; j < 4; j++) dm += dmag[(b * 4 + j) * LSEQ + l];
        }
        sc[t] = 1.f + softplusf(dm * 0.25f);
    }
#pragma unroll
    for (int e = 0; e < 8; e++) {
        int idx = t + 256 * e;             // 0..2047
        int ll = idx >> 6, dj = idx & 63;
        int l = lt0 + ll;
        float uu = 0.f, zz = 0.f;
        if (l < LSEQ) {
            uu = xm[((size_t)(b * LSEQ + l)) * 512 + dt0 + dj];
            zz = xz[((size_t)(b * LSEQ + l)) * 1024 + 512 + dt0 + dj];
        }
        xmu[ll][dj] = uu;
        xzs[ll][dj] = zz;
    }
    __syncthreads();

    const int ll = t & 31;
    const int l  = lt0 + ll;
#pragma unroll
    for (int e = 0; e < 8; e++) {
        int dl = (t >> 5) * 8 + e;
        float acc = b_dt[dt0 + dl];
#pragma unroll
        for (int i = 0; i < 16; i++)
            acc = fmaf(xr[ll][i], Wl[i][dl], acc);
        float dtv = softplusf(acc) * sc[ll];
        float uu  = xmu[ll][dl];
        float sz  = siluf(xzs[ll][dl]);
        if (l < LSEQ)
            dtq[((size_t)(b * 512 + dt0 + dl)) * LSEQ + l] =
                make_float4(dtv, dtv * uu, uu, sz);
    }
}

// ---------------------------------------------------------------------------
// Selective scan v3: one wave per (b,d), lane = state n. T=8 steps/iter,
// prefetched loads, wave-uniform dtq (128B contig), lane-contig bcq (4x b128),
// deferred reduce-scatter butterfly, register epilogue, 32B contig store.
// ---------------------------------------------------------------------------
__global__ __launch_bounds__(256) void scan_k(
    const float4* __restrict__ dtq, const float* __restrict__ bcq,
    const float* __restrict__ A_log, const float* __restrict__ D_skip,
    float* __restrict__ y2)
{
    int wv0  = blockIdx.x * 4 + (threadIdx.x >> 6);      // 0..4095
    int wv   = __builtin_amdgcn_readfirstlane(wv0);
    int lane = threadIdx.x & 63;
    int b = wv >> 9;
    int d = wv & 511;

    float A  = -__expf(A_log[d * 64 + lane]);
    float Dd = D_skip[d];

    const float4* dqp = dtq + (size_t)(b * 512 + d) * LSEQ;
    const float*  bcb = bcq + ((size_t)b * 25 * 64 + lane) * 16;
    float*        yp  = y2  + (size_t)(b * 512 + d) * LSEQ;

    const bool lo32 = (lane & 32) == 0;
    const bool lo16 = (lane & 16) == 0;
    const bool lo8  = (lane & 8)  == 0;
    const bool store_lane = (lane & 7) == 0;
    const int  tsel = lane >> 3;

    float4 bcv[4], dqv[8];
#pragma unroll
    for (int i = 0; i < 4; i++) bcv[i] = *(const float4*)(bcb + i * 4);
#pragma unroll
    for (int t = 0; t < 8; t++) dqv[t] = dqp[t];

    float h = 0.f;
    for (int l0 = 0; l0 < LSEQ; l0 += 8) {
        // prefetch next block (last iter refetches block 24; discarded)
        int ln = (l0 + 8 < LSEQ) ? (l0 + 8) : 192;
        float4 bcn[4], dqn[8];
#pragma unroll
        for (int i = 0; i < 4; i++)
            bcn[i] = *(const float4*)(bcb + (size_t)(ln >> 3) * 1024 + i * 4);
#pragma unroll
        for (int t = 0; t < 8; t++) dqn[t] = dqp[ln + t];

        // recurrence (only h is serial)
        float p[8];
#pragma unroll
        for (int t = 0; t < 8; t++) {
            float Bv = (t & 1) ? bcv[t >> 1].z : bcv[t >> 1].x;
            float Cv = (t & 1) ? bcv[t >> 1].w : bcv[t >> 1].y;
            float e = __expf(dqv[t].x * A);
            h = fmaf(e, h, dqv[t].y * Bv);
            p[t] = h * Cv;
        }

        // reduce-scatter butterfly: lane L ends with Y[L>>3]
        float q[4];
#pragma unroll
        for (int i = 0; i < 4; i++) {
            float keep = lo32 ? p[i] : p[i + 4];
            float send = lo32 ? p[i + 4] : p[i];
            q[i] = keep + __shfl_xor(send, 32, 64);
        }
        float r2[2];
#pragma unroll
        for (int i = 0; i < 2; i++) {
            float keep = lo16 ? q[i] : q[i + 2];
            float send = lo16 ? q[i + 2] : q[i];
            r2[i] = keep + __shfl_xor(send, 16, 64);
        }
        float keep = lo8 ? r2[0] : r2[1];
        float send = lo8 ? r2[1] : r2[0];
        float s = keep + __shfl_xor(send, 8, 64);
        s += __shfl_xor(s, 4, 64);
        s += __shfl_xor(s, 2, 64);
        s += __shfl_xor(s, 1, 64);

        // register epilogue: y = (Y + u*D) * silu(z); 8 lanes store 32B contig
        float u_arr[8], sz_arr[8];
#pragma unroll
        for (int t = 0; t < 8; t++) { u_arr[t] = dqv[t].z; sz_arr[t] = dqv[t].w; }
        float usel  = mux8(u_arr, tsel);
        float szsel = mux8(sz_arr, tsel);
        float yv = (s + usel * Dd) * szsel;
        if (store_lane) yp[l0 + tsel] = yv;

#pragma unroll
        for (int i = 0; i < 4; i++) bcv[i] = bcn[i];
#pragma unroll
        for (int t = 0; t < 8; t++) dqv[t] = dqn[t];
    }
}

// ---------------------------------------------------------------------------
// Transpose y2 [b][d][l] -> split bf16 [r=b*200+l][d] for the W_out GEMM.
// ---------------------------------------------------------------------------
__global__ __launch_bounds__(256) void yT_k(
    const float* __restrict__ y2,
    unsigned short* __restrict__ y_hi, unsigned short* __restrict__ y_lo)
{
    __shared__ float tile[64][65];
    const int b   = blockIdx.z;
    const int dt0 = blockIdx.y * 64;
    const int lt0 = blockIdx.x * 64;
    const int t   = threadIdx.x;

#pragma unroll
    for (int e = 0; e < 16; e++) {
        int idx = t + 256 * e;             // 0..4095
        int dl = idx >> 6, ll = idx & 63;
        int l = lt0 + ll;
        tile[dl][ll] = (l < LSEQ) ? y2[((size_t)(b * 512 + dt0 + dl)) * LSEQ + l] : 0.f;
    }
    __syncthreads();
#pragma unroll
    for (int e = 0; e < 16; e++) {
        int idx = t + 256 * e;
        int ll = idx >> 6, dl = idx & 63;
        int l = lt0 + ll;
        if (l < LSEQ) {
            float v = tile[dl][ll];
            unsigned short h = f2bf(v);
            size_t o = ((size_t)(b * LSEQ + l)) * 512 + dt0 + dl;
            y_hi[o] = h;
            y_lo[o] = f2bf(v - bf2f(h));
        }
    }
}

// ---------------------------------------------------------------------------
// LayerNorm over last dim (256) + gamma/beta, fp32 out
// ---------------------------------------------------------------------------
__global__ __launch_bounds__(256) void ln_k(
    const float* __restrict__ outp, const float* __restrict__ gamma,
    const float* __restrict__ beta, float* __restrict__ out)
{
    int r = blockIdx.x;
    int t = threadIdx.x;
    float v = outp[(size_t)r * 256 + t];
    float s = v, ss = v * v;
#pragma unroll
    for (int off = 32; off > 0; off >>= 1) {
        s  += __shfl_xor(s,  off, 64);
        ss += __shfl_xor(ss, off, 64);
    }
    __shared__ float red[8];
    int w = t >> 6;
    if ((t & 63) == 0) { red[w] = s; red[4 + w] = ss; }
    __syncthreads();
    s  = red[0] + red[1] + red[2] + red[3];
    ss = red[4] + red[5] + red[6] + red[7];
    float mu  = s * (1.f / 256.f);
    float var = ss * (1.f / 256.f) - mu * mu;
    if (var < 0.f) var = 0.f;
    float inv = rsqrtf(var + 1e-12f);
    float o = (v - mu) * inv * gamma[t] + beta[t];
    out[(size_t)r * 256 + t] = o;
}

// ---------------------------------------------------------------------------
extern "C" void kernel_launch(void* const* d_in, const int* in_sizes, int n_in,
                              void* d_out, int out_size, void* d_ws, size_t ws_size,
                              hipStream_t stream)
{
    const float* x       = (const float*)d_in[0];
    const float* cosp    = (const float*)d_in[1];
    const float* sinp    = (const float*)d_in[2];
    const float* dmag    = (const float*)d_in[3];
    const float* W_in    = (const float*)d_in[4];
    const float* conv_w  = (const float*)d_in[5];
    const float* conv_b  = (const float*)d_in[6];
    const float* W_x     = (const float*)d_in[7];
    const float* W_dt    = (const float*)d_in[8];
    const float* b_dt    = (const float*)d_in[9];
    const float* A_log   = (const float*)d_in[10];
    const float* D_skip  = (const float*)d_in[11];
    const float* W_out   = (const float*)d_in[12];
    const float* gamma   = (const float*)d_in[13];
    const float* beta    = (const float*)d_in[14];
    const float* W_phase = (const float*)d_in[15];
    float* out = (float*)d_out;

    char* ws = (char*)d_ws;
    float*  xz     = (float*)ws;  ws += (size_t)ROWS * 1024 * 4;
    float*  xm     = (float*)ws;  ws += (size_t)ROWS * 512 * 4;
    float*  xp     = (float*)ws;  ws += (size_t)ROWS * 144 * 4;
    float*  bcq    = (float*)ws;  ws += (size_t)ROWS * 128 * 4;
    float4* dtq    = (float4*)ws; ws += (size_t)B_SZ * 512 * LSEQ * 16;
    float*  y2     = (float*)ws;  ws += (size_t)ROWS * 512 * 4;
    float*  outp   = (float*)ws;  ws += (size_t)ROWS * 256 * 4;
    unsigned short* x_hi   = (unsigned short*)ws; ws += (size_t)ROWS * 256 * 2;
    unsigned short* x_lo   = (unsigned short*)ws; ws += (size_t)ROWS * 256 * 2;
    unsigned short* WiT_hi = (unsigned short*)ws; ws += (size_t)1024 * 256 * 2;
    unsigned short* WiT_lo = (unsigned short*)ws; ws += (size_t)1024 * 256 * 2;
    unsigned short* WxT_hi = (unsigned short*)ws; ws += (size_t)144 * 512 * 2;
    unsigned short* WxT_lo = (unsigned short*)ws; ws += (size_t)144 * 512 * 2;
    unsigned short* WoT_hi = (unsigned short*)ws; ws += (size_t)256 * 512 * 2;
    unsigned short* WoT_lo = (unsigned short*)ws; ws += (size_t)256 * 512 * 2;
    unsigned short* xm_hi  = (unsigned short*)ws; ws += (size_t)ROWS * 512 * 2;
    unsigned short* xm_lo  = (unsigned short*)ws; ws += (size_t)ROWS * 512 * 2;
    unsigned short* yf_hi  = (unsigned short*)ws; ws += (size_t)ROWS * 512 * 2;
    unsigned short* yf_lo  = (unsigned short*)ws; ws += (size_t)ROWS * 512 * 2;

    dim3 blk(256);
    prep_w_k   <<<dim3(3424),    blk, 0, stream>>>(x, W_in, W_x, W_out,
                                                   x_hi, x_lo, WiT_hi, WiT_lo,
                                                   WxT_hi, WxT_lo, WoT_hi, WoT_lo);
    gemm_mfma  <<<dim3(16, 25),  blk, 0, stream>>>(x_hi, x_lo, WiT_hi, WiT_lo,
                                                   xz, ROWS, 1024, 256, nullptr);
    conv_silu_k<<<dim3(3200),    blk, 0, stream>>>(xz, conv_w, conv_b, xm, xm_hi, xm_lo);
    gemm_mfma  <<<dim3(3, 25),   blk, 0, stream>>>(xm_hi, xm_lo, WxT_hi, WxT_lo,
                                                   xp, ROWS, 144, 512, nullptr);
    pack_bc_k  <<<dim3(400),     blk, 0, stream>>>(cosp, sinp, W_phase, xp, bcq);
    dtq_k      <<<dim3(7, 8, 8), blk, 0, stream>>>(xp, W_dt, b_dt, dmag, xm, xz, dtq);
    scan_k     <<<dim3(1024),    blk, 0, stream>>>(dtq, bcq, A_log, D_skip, y2);
    yT_k       <<<dim3(4, 8, 8), blk, 0, stream>>>(y2, yf_hi, yf_lo);
    gemm_mfma  <<<dim3(4, 25),   blk, 0, stream>>>(yf_hi, yf_lo, WoT_hi, WoT_lo,
                                                   outp, ROWS, 256, 512, x);
    ln_k       <<<dim3(1600),    blk, 0, stream>>>(outp, gamma, beta, out);
}

// Round 6
// 197.556 us; speedup vs baseline: 1.0169x; 1.0169x over previous
//
#include <hip/hip_runtime.h>
#include <hip/hip_bf16.h>

#define B_SZ 8
#define LSEQ 200
#define DMODEL 256
#define DINNER 512
#define DSTATE 64
#define DTRANK 16
#define ROWS (B_SZ * LSEQ)   // 1600

using bf16x8 = __attribute__((ext_vector_type(8))) short;
using f32x4  = __attribute__((ext_vector_type(4))) float;

__device__ __forceinline__ float softplusf(float x) {
    return (x > 20.f) ? x : log1pf(__expf(x));
}
__device__ __forceinline__ float siluf(float x) {
    return x / (1.f + __expf(-x));
}
__device__ __forceinline__ unsigned short f2bf(float f) {
    union { float f; unsigned int u; } v; v.f = f;
    unsigned int r = v.u + 0x7FFF + ((v.u >> 16) & 1);   // RNE
    return (unsigned short)(r >> 16);
}
__device__ __forceinline__ float bf2f(unsigned short u) {
    union { unsigned int i; float f; } v;
    v.i = ((unsigned int)u) << 16;
    return v.f;
}

// DPP-based wave64 sum: after this chain lane 63 holds the full sum.
// VALU-latency ops only (no LDS / ds_bpermute on the critical path).
#define DPP_ADD(x, ctrl, rmask, bmask)                                         \
    ((x) + __builtin_bit_cast(float, __builtin_amdgcn_update_dpp(              \
               0, __builtin_bit_cast(int, (x)), (ctrl), (rmask), (bmask), false)))

__device__ __forceinline__ float wave_sum_dpp(float x) {
    x = DPP_ADD(x, 0x111, 0xf, 0xf);   // row_shr:1
    x = DPP_ADD(x, 0x112, 0xf, 0xf);   // row_shr:2
    x = DPP_ADD(x, 0x114, 0xf, 0xe);   // row_shr:4
    x = DPP_ADD(x, 0x118, 0xf, 0xc);   // row_shr:8  -> lane15 of each row = row sum
    x = DPP_ADD(x, 0x142, 0xa, 0xf);   // row_bcast:15 -> lanes 31/63 = half sums
    x = DPP_ADD(x, 0x143, 0xc, 0xf);   // row_bcast:31 -> lane 63 = total
    return x;
}

// ---------------------------------------------------------------------------
// One-time prep: split x into bf16 hi/lo; transpose+split W_in, W_x, W_out
// into [N][K] k-contiguous bf16 hi/lo (B-operand layout for MFMA).
// ---------------------------------------------------------------------------
__global__ __launch_bounds__(256) void prep_w_k(
    const float* __restrict__ x, const float* __restrict__ W_in,
    const float* __restrict__ W_x, const float* __restrict__ W_out,
    unsigned short* __restrict__ x_hi,  unsigned short* __restrict__ x_lo,
    unsigned short* __restrict__ WiT_hi, unsigned short* __restrict__ WiT_lo,
    unsigned short* __restrict__ WxT_hi, unsigned short* __restrict__ WxT_lo,
    unsigned short* __restrict__ WoT_hi, unsigned short* __restrict__ WoT_lo)
{
    int idx = blockIdx.x * 256 + threadIdx.x;
    float v;
    unsigned short *dh, *dl;
    size_t di;
    if (idx < 409600) {                       // x: straight split (k-contig already)
        v = x[idx]; dh = x_hi; dl = x_lo; di = idx;
    } else if (idx < 409600 + 262144) {       // W_in [256][1024] -> WiT [1024][256]
        int l = idx - 409600;
        int n = l >> 8, k = l & 255;
        v = W_in[(size_t)k * 1024 + n]; dh = WiT_hi; dl = WiT_lo; di = l;
    } else if (idx < 409600 + 262144 + 73728) { // W_x [512][144] -> WxT [144][512]
        int l = idx - (409600 + 262144);
        int n = l >> 9, k = l & 511;
        v = W_x[(size_t)k * 144 + n]; dh = WxT_hi; dl = WxT_lo; di = l;
    } else if (idx < 409600 + 262144 + 73728 + 131072) { // W_out [512][256] -> WoT [256][512]
        int l = idx - (409600 + 262144 + 73728);
        int n = l >> 9, k = l & 511;
        v = W_out[(size_t)k * 256 + n]; dh = WoT_hi; dl = WoT_lo; di = l;
    } else return;
    unsigned short h = f2bf(v);
    dh[di] = h;
    dl[di] = f2bf(v - bf2f(h));
}

// ---------------------------------------------------------------------------
// Split-bf16 MFMA GEMM: hi·hi + hi·lo + lo·hi. 64x64 tile, 4 waves of 32x32.
// ---------------------------------------------------------------------------
__global__ __launch_bounds__(256) void gemm_mfma(
    const unsigned short* __restrict__ A_hi, const unsigned short* __restrict__ A_lo,
    const unsigned short* __restrict__ BT_hi, const unsigned short* __restrict__ BT_lo,
    float* __restrict__ C, int M, int N, int K, const float* __restrict__ resid)
{
    __shared__ unsigned short As_hi[64 * 40], As_lo[64 * 40];
    __shared__ unsigned short Bs_hi[64 * 40], Bs_lo[64 * 40];

    const int t    = threadIdx.x;
    const int m0   = blockIdx.y * 64;
    const int n0   = blockIdx.x * 64;
    const int lane = t & 63;
    const int w    = t >> 6;
    const int wm   = (w >> 1) * 32;
    const int wn   = (w & 1) * 32;
    const int fr   = lane & 15;
    const int fq   = lane >> 4;

    const int sr = t >> 2;
    const int sc = (t & 3) * 8;

    f32x4 acc[2][2] = {};

    const size_t a_off = (size_t)(m0 + sr) * K + sc;
    const int    brow  = n0 + sr;
    const size_t b_off = (size_t)brow * K + sc;
    const bool   bok   = brow < N;

    for (int k0 = 0; k0 < K; k0 += 32) {
        int4 ah = *(const int4*)(A_hi + a_off + k0);
        int4 al = *(const int4*)(A_lo + a_off + k0);
        int4 bh = make_int4(0, 0, 0, 0), bl = make_int4(0, 0, 0, 0);
        if (bok) {
            bh = *(const int4*)(BT_hi + b_off + k0);
            bl = *(const int4*)(BT_lo + b_off + k0);
        }
        __syncthreads();
        *(int4*)&As_hi[sr * 40 + sc] = ah;
        *(int4*)&As_lo[sr * 40 + sc] = al;
        *(int4*)&Bs_hi[sr * 40 + sc] = bh;
        *(int4*)&Bs_lo[sr * 40 + sc] = bl;
        __syncthreads();

        bf16x8 a_h[2], a_l[2], b_h[2], b_l[2];
#pragma unroll
        for (int mi = 0; mi < 2; mi++) {
            int row = wm + mi * 16 + fr;
            a_h[mi] = *(const bf16x8*)&As_hi[row * 40 + fq * 8];
            a_l[mi] = *(const bf16x8*)&As_lo[row * 40 + fq * 8];
        }
#pragma unroll
        for (int ni = 0; ni < 2; ni++) {
            int row = wn + ni * 16 + fr;
            b_h[ni] = *(const bf16x8*)&Bs_hi[row * 40 + fq * 8];
            b_l[ni] = *(const bf16x8*)&Bs_lo[row * 40 + fq * 8];
        }
#pragma unroll
        for (int mi = 0; mi < 2; mi++)
#pragma unroll
            for (int ni = 0; ni < 2; ni++) {
                acc[mi][ni] = __builtin_amdgcn_mfma_f32_16x16x32_bf16(a_h[mi], b_h[ni], acc[mi][ni], 0, 0, 0);
                acc[mi][ni] = __builtin_amdgcn_mfma_f32_16x16x32_bf16(a_h[mi], b_l[ni], acc[mi][ni], 0, 0, 0);
                acc[mi][ni] = __builtin_amdgcn_mfma_f32_16x16x32_bf16(a_l[mi], b_h[ni], acc[mi][ni], 0, 0, 0);
            }
    }

#pragma unroll
    for (int mi = 0; mi < 2; mi++)
#pragma unroll
        for (int ni = 0; ni < 2; ni++) {
            int col = n0 + wn + ni * 16 + fr;
            if (col < N) {
#pragma unroll
                for (int reg = 0; reg < 4; reg++) {
                    int row = m0 + wm + mi * 16 + fq * 4 + reg;
                    float v = acc[mi][ni][reg];
                    if (resid) v += resid[(size_t)row * N + col];
                    C[(size_t)row * N + col] = v;
                }
            }
        }
}

// ---------------------------------------------------------------------------
// Depthwise causal conv (width 4) + bias + silu; emits fp32 + split bf16.
// ---------------------------------------------------------------------------
__global__ __launch_bounds__(256) void conv_silu_k(
    const float* __restrict__ xz, const float* __restrict__ conv_w,
    const float* __restrict__ conv_b, float* __restrict__ xm,
    unsigned short* __restrict__ xm_hi, unsigned short* __restrict__ xm_lo)
{
    int idx = blockIdx.x * 256 + threadIdx.x;   // < ROWS*512 = 819200
    int c = idx & 511;
    int r = idx >> 9;
    int l = r % LSEQ;

    float w0 = conv_w[c * 4 + 0];
    float w1 = conv_w[c * 4 + 1];
    float w2 = conv_w[c * 4 + 2];
    float w3 = conv_w[c * 4 + 3];

    const float* base = xz + (size_t)r * 1024 + c;
    float acc = conv_b[c];
    if (l >= 3) acc = fmaf(base[-3 * 1024], w0, acc);
    if (l >= 2) acc = fmaf(base[-2 * 1024], w1, acc);
    if (l >= 1) acc = fmaf(base[-1 * 1024], w2, acc);
    acc = fmaf(base[0], w3, acc);

    float s = siluf(acc);
    xm[idx] = s;
    unsigned short h = f2bf(s);
    xm_hi[idx] = h;
    xm_lo[idx] = f2bf(s - bf2f(h));
}

// ---------------------------------------------------------------------------
// Pack B and C (with phase modulation) into lane-contiguous 8-step tiles:
// bcq[b][lblk][n][t][2]  (lblk = l>>3, t = l&7)
// ---------------------------------------------------------------------------
__global__ __launch_bounds__(256) void pack_bc_k(
    const float* __restrict__ cosp, const float* __restrict__ sinp,
    const float* __restrict__ W_phase, const float* __restrict__ xp,
    float* __restrict__ bcq)
{
    int idx = blockIdx.x * 256 + threadIdx.x;   // < ROWS*64 = 102400
    int n = idx & 63;
    int r = idx >> 6;
    int b = r / LSEQ, l = r % LSEQ;

    float acc = 0.f;
#pragma unroll
    for (int j = 0; j < 4; j++) {
        float cp = cosp[(b * 4 + j) * LSEQ + l];
        float sp = sinp[(b * 4 + j) * LSEQ + l];
        acc = fmaf(cp, W_phase[j * 64 + n], acc);
        acc = fmaf(sp, W_phase[(4 + j) * 64 + n], acc);
    }
    float Bv = xp[(size_t)r * 144 + 16 + n];
    float Cv = xp[(size_t)r * 144 + 80 + n] + acc;
    size_t o = ((((size_t)b * 25 + (l >> 3)) * 64 + n) * 8 + (l & 7)) * 2;
    *(float2*)&bcq[o] = make_float2(Bv, Cv);
}

// ---------------------------------------------------------------------------
// dtq_k: writes dtq[b][d][l] = (dt, dt*u, u, silu(z))  -- l-contiguous float4.
// ---------------------------------------------------------------------------
__global__ __launch_bounds__(256) void dtq_k(
    const float* __restrict__ xp, const float* __restrict__ W_dt,
    const float* __restrict__ b_dt, const float* __restrict__ dmag,
    const float* __restrict__ xm, const float* __restrict__ xz,
    float4* __restrict__ dtq)
{
    const int b   = blockIdx.z;
    const int dt0 = blockIdx.y * 64;
    const int lt0 = blockIdx.x * 32;
    const int t   = threadIdx.x;

    __shared__ float Wl[16][64];
    __shared__ float xr[32][17];
    __shared__ float sc[32];
    __shared__ float xmu[32][64];
    __shared__ float xzs[32][64];

#pragma unroll
    for (int e = 0; e < 4; e++) {
        int idx = t + 256 * e;
        int i = idx >> 6, j = idx & 63;
        Wl[i][j] = W_dt[i * 512 + dt0 + j];
    }
#pragma unroll
    for (int e = 0; e < 2; e++) {
        int idx = t + 256 * e;
        int ll = idx >> 4, i = idx & 15;
        int l = lt0 + ll;
        xr[ll][i] = (l < LSEQ) ? xp[((size_t)(b * LSEQ + l)) * 144 + i] : 0.f;
    }
    if (t < 32) {
        int l = lt0 + t;
        float dm = 0.f;
        if (l < LSEQ) {
#pragma unroll
            for (int j = 0; j < 4; j++) dm += dmag[(b * 4 + j) * LSEQ + l];
        }
        sc[t] = 1.f + softplusf(dm * 0.25f);
    }
#pragma unroll
    for (int e = 0; e < 8; e++) {
        int idx = t + 256 * e;
        int ll = idx >> 6, dj = idx & 63;
        int l = lt0 + ll;
        float uu = 0.f, zz = 0.f;
        if (l < LSEQ) {
            uu = xm[((size_t)(b * LSEQ + l)) * 512 + dt0 + dj];
            zz = xz[((size_t)(b * LSEQ + l)) * 1024 + 512 + dt0 + dj];
        }
        xmu[ll][dj] = uu;
        xzs[ll][dj] = zz;
    }
    __syncthreads();

    const int ll = t & 31;
    const int l  = lt0 + ll;
#pragma unroll
    for (int e = 0; e < 8; e++) {
        int dl = (t >> 5) * 8 + e;
        float acc = b_dt[dt0 + dl];
#pragma unroll
        for (int i = 0; i < 16; i++)
            acc = fmaf(xr[ll][i], Wl[i][dl], acc);
        float dtv = softplusf(acc) * sc[ll];
        float uu  = xmu[ll][dl];
        float sz  = siluf(xzs[ll][dl]);
        if (l < LSEQ)
            dtq[((size_t)(b * 512 + dt0 + dl)) * LSEQ + l] =
                make_float4(dtv, dtv * uu, uu, sz);
    }
}

// ---------------------------------------------------------------------------
// Selective scan v4: one wave per (b,d), lane = state n. T=8 steps/iter,
// prefetched loads; per-step DPP wave-sum (VALU-only, lane 63 gets total);
// register epilogue (no mux, u/sz wave-uniform); lane 63 stores 32B contig.
// ---------------------------------------------------------------------------
__global__ __launch_bounds__(256) void scan_k(
    const float4* __restrict__ dtq, const float* __restrict__ bcq,
    const float* __restrict__ A_log, const float* __restrict__ D_skip,
    float* __restrict__ y2)
{
    int wv0  = blockIdx.x * 4 + (threadIdx.x >> 6);      // 0..4095
    int wv   = __builtin_amdgcn_readfirstlane(wv0);
    int lane = threadIdx.x & 63;
    int b = wv >> 9;
    int d = wv & 511;

    float A  = -__expf(A_log[d * 64 + lane]);
    float Dd = D_skip[d];

    const float4* dqp = dtq + (size_t)(b * 512 + d) * LSEQ;
    const float*  bcb = bcq + ((size_t)b * 25 * 64 + lane) * 16;
    float*        yp  = y2  + (size_t)(b * 512 + d) * LSEQ;

    const bool wlane = (lane == 63);

    float4 bcv[4], dqv[8];
#pragma unroll
    for (int i = 0; i < 4; i++) bcv[i] = *(const float4*)(bcb + i * 4);
#pragma unroll
    for (int t = 0; t < 8; t++) dqv[t] = dqp[t];

    float h = 0.f;
    for (int l0 = 0; l0 < LSEQ; l0 += 8) {
        // prefetch next block (last iter refetches block 24; discarded)
        int ln = (l0 + 8 < LSEQ) ? (l0 + 8) : 192;
        float4 bcn[4], dqn[8];
#pragma unroll
        for (int i = 0; i < 4; i++)
            bcn[i] = *(const float4*)(bcb + (size_t)(ln >> 3) * 1024 + i * 4);
#pragma unroll
        for (int t = 0; t < 8; t++) dqn[t] = dqp[ln + t];

        // recurrence (only h is serial); per-step DPP reduce + epilogue
        float yv[8];
#pragma unroll
        for (int t = 0; t < 8; t++) {
            float Bv = (t & 1) ? bcv[t >> 1].z : bcv[t >> 1].x;
            float Cv = (t & 1) ? bcv[t >> 1].w : bcv[t >> 1].y;
            float e = __expf(dqv[t].x * A);
            h = fmaf(e, h, dqv[t].y * Bv);
            float s = wave_sum_dpp(h * Cv);          // lane 63: full 64-state sum
            yv[t] = (s + dqv[t].z * Dd) * dqv[t].w;  // u, silu(z) wave-uniform
        }

        if (wlane) {
            *(float4*)&yp[l0]     = make_float4(yv[0], yv[1], yv[2], yv[3]);
            *(float4*)&yp[l0 + 4] = make_float4(yv[4], yv[5], yv[6], yv[7]);
        }

#pragma unroll
        for (int i = 0; i < 4; i++) bcv[i] = bcn[i];
#pragma unroll
        for (int t = 0; t < 8; t++) dqv[t] = dqn[t];
    }
}

// ---------------------------------------------------------------------------
// Transpose y2 [b][d][l] -> split bf16 [r=b*200+l][d] for the W_out GEMM.
// ---------------------------------------------------------------------------
__global__ __launch_bounds__(256) void yT_k(
    const float* __restrict__ y2,
    unsigned short* __restrict__ y_hi, unsigned short* __restrict__ y_lo)
{
    __shared__ float tile[64][65];
    const int b   = blockIdx.z;
    const int dt0 = blockIdx.y * 64;
    const int lt0 = blockIdx.x * 64;
    const int t   = threadIdx.x;

#pragma unroll
    for (int e = 0; e < 16; e++) {
        int idx = t + 256 * e;
        int dl = idx >> 6, ll = idx & 63;
        int l = lt0 + ll;
        tile[dl][ll] = (l < LSEQ) ? y2[((size_t)(b * 512 + dt0 + dl)) * LSEQ + l] : 0.f;
    }
    __syncthreads();
#pragma unroll
    for (int e = 0; e < 16; e++) {
        int idx = t + 256 * e;
        int ll = idx >> 6, dl = idx & 63;
        int l = lt0 + ll;
        if (l < LSEQ) {
            float v = tile[dl][ll];
            unsigned short h = f2bf(v);
            size_t o = ((size_t)(b * LSEQ + l)) * 512 + dt0 + dl;
            y_hi[o] = h;
            y_lo[o] = f2bf(v - bf2f(h));
        }
    }
}

// ---------------------------------------------------------------------------
// LayerNorm over last dim (256) + gamma/beta, fp32 out
// ---------------------------------------------------------------------------
__global__ __launch_bounds__(256) void ln_k(
    const float* __restrict__ outp, const float* __restrict__ gamma,
    const float* __restrict__ beta, float* __restrict__ out)
{
    int r = blockIdx.x;
    int t = threadIdx.x;
    float v = outp[(size_t)r * 256 + t];
    float s = v, ss = v * v;
#pragma unroll
    for (int off = 32; off > 0; off >>= 1) {
        s  += __shfl_xor(s,  off, 64);
        ss += __shfl_xor(ss, off, 64);
    }
    __shared__ float red[8];
    int w = t >> 6;
    if ((t & 63) == 0) { red[w] = s; red[4 + w] = ss; }
    __syncthreads();
    s  = red[0] + red[1] + red[2] + red[3];
    ss = red[4] + red[5] + red[6] + red[7];
    float mu  = s * (1.f / 256.f);
    float var = ss * (1.f / 256.f) - mu * mu;
    if (var < 0.f) var = 0.f;
    float inv = rsqrtf(var + 1e-12f);
    float o = (v - mu) * inv * gamma[t] + beta[t];
    out[(size_t)r * 256 + t] = o;
}

// ---------------------------------------------------------------------------
extern "C" void kernel_launch(void* const* d_in, const int* in_sizes, int n_in,
                              void* d_out, int out_size, void* d_ws, size_t ws_size,
                              hipStream_t stream)
{
    const float* x       = (const float*)d_in[0];
    const float* cosp    = (const float*)d_in[1];
    const float* sinp    = (const float*)d_in[2];
    const float* dmag    = (const float*)d_in[3];
    const float* W_in    = (const float*)d_in[4];
    const float* conv_w  = (const float*)d_in[5];
    const float* conv_b  = (const float*)d_in[6];
    const float* W_x     = (const float*)d_in[7];
    const float* W_dt    = (const float*)d_in[8];
    const float* b_dt    = (const float*)d_in[9];
    const float* A_log   = (const float*)d_in[10];
    const float* D_skip  = (const float*)d_in[11];
    const float* W_out   = (const float*)d_in[12];
    const float* gamma   = (const float*)d_in[13];
    const float* beta    = (const float*)d_in[14];
    const float* W_phase = (const float*)d_in[15];
    float* out = (float*)d_out;

    char* ws = (char*)d_ws;
    float*  xz     = (float*)ws;  ws += (size_t)ROWS * 1024 * 4;
    float*  xm     = (float*)ws;  ws += (size_t)ROWS * 512 * 4;
    float*  xp     = (float*)ws;  ws += (size_t)ROWS * 144 * 4;
    float*  bcq    = (float*)ws;  ws += (size_t)ROWS * 128 * 4;
    float4* dtq    = (float4*)ws; ws += (size_t)B_SZ * 512 * LSEQ * 16;
    float*  y2     = (float*)ws;  ws += (size_t)ROWS * 512 * 4;
    float*  outp   = (float*)ws;  ws += (size_t)ROWS * 256 * 4;
    unsigned short* x_hi   = (unsigned short*)ws; ws += (size_t)ROWS * 256 * 2;
    unsigned short* x_lo   = (unsigned short*)ws; ws += (size_t)ROWS * 256 * 2;
    unsigned short* WiT_hi = (unsigned short*)ws; ws += (size_t)1024 * 256 * 2;
    unsigned short* WiT_lo = (unsigned short*)ws; ws += (size_t)1024 * 256 * 2;
    unsigned short* WxT_hi = (unsigned short*)ws; ws += (size_t)144 * 512 * 2;
    unsigned short* WxT_lo = (unsigned short*)ws; ws += (size_t)144 * 512 * 2;
    unsigned short* WoT_hi = (unsigned short*)ws; ws += (size_t)256 * 512 * 2;
    unsigned short* WoT_lo = (unsigned short*)ws; ws += (size_t)256 * 512 * 2;
    unsigned short* xm_hi  = (unsigned short*)ws; ws += (size_t)ROWS * 512 * 2;
    unsigned short* xm_lo  = (unsigned short*)ws; ws += (size_t)ROWS * 512 * 2;
    unsigned short* yf_hi  = (unsigned short*)ws; ws += (size_t)ROWS * 512 * 2;
    unsigned short* yf_lo  = (unsigned short*)ws; ws += (size_t)ROWS * 512 * 2;

    dim3 blk(256);
    prep_w_k   <<<dim3(3424),    blk, 0, stream>>>(x, W_in, W_x, W_out,
                                                   x_hi, x_lo, WiT_hi, WiT_lo,
                                                   WxT_hi, WxT_lo, WoT_hi, WoT_lo);
    gemm_mfma  <<<dim3(16, 25),  blk, 0, stream>>>(x_hi, x_lo, WiT_hi, WiT_lo,
                                                   xz, ROWS, 1024, 256, nullptr);
    conv_silu_k<<<dim3(3200),    blk, 0, stream>>>(xz, conv_w, conv_b, xm, xm_hi, xm_lo);
    gemm_mfma  <<<dim3(3, 25),   blk, 0, stream>>>(xm_hi, xm_lo, WxT_hi, WxT_lo,
                                                   xp, ROWS, 144, 512, nullptr);
    pack_bc_k  <<<dim3(400),     blk, 0, stream>>>(cosp, sinp, W_phase, xp, bcq);
    dtq_k      <<<dim3(7, 8, 8), blk, 0, stream>>>(xp, W_dt, b_dt, dmag, xm, xz, dtq);
    scan_k     <<<dim3(1024),    blk, 0, stream>>>(dtq, bcq, A_log, D_skip, y2);
    yT_k       <<<dim3(4, 8, 8), blk, 0, stream>>>(y2, yf_hi, yf_lo);
    gemm_mfma  <<<dim3(4, 25),   blk, 0, stream>>>(yf_hi, yf_lo, WoT_hi, WoT_lo,
                                                   outp, ROWS, 256, 512, x);
    ln_k       <<<dim3(1600),    blk, 0, stream>>>(outp, gamma, beta, out);
}

// Round 7
// 185.758 us; speedup vs baseline: 1.0815x; 1.0635x over previous
//
#include <hip/hip_runtime.h>
#include <hip/hip_bf16.h>

#define B_SZ 8
#define LSEQ 200
#define DMODEL 256
#define DINNER 512
#define DSTATE 64
#define DTRANK 16
#define ROWS (B_SZ * LSEQ)   // 1600

using bf16x8 = __attribute__((ext_vector_type(8))) short;
using f32x4  = __attribute__((ext_vector_type(4))) float;

__device__ __forceinline__ float softplusf(float x) {
    return (x > 20.f) ? x : log1pf(__expf(x));
}
__device__ __forceinline__ float siluf(float x) {
    return x / (1.f + __expf(-x));
}
__device__ __forceinline__ unsigned short f2bf(float f) {
    union { float f; unsigned int u; } v; v.f = f;
    unsigned int r = v.u + 0x7FFF + ((v.u >> 16) & 1);   // RNE
    return (unsigned short)(r >> 16);
}
__device__ __forceinline__ float bf2f(unsigned short u) {
    union { unsigned int i; float f; } v;
    v.i = ((unsigned int)u) << 16;
    return v.f;
}
// 8-way mux by 3-bit divergent selector — SCALAR args (no array → no LDS scratch)
__device__ __forceinline__ float mux8s(float v0, float v1, float v2, float v3,
                                       float v4, float v5, float v6, float v7, int s) {
    float a = (s & 1) ? v1 : v0;
    float b = (s & 1) ? v3 : v2;
    float c = (s & 1) ? v5 : v4;
    float d = (s & 1) ? v7 : v6;
    float e = (s & 2) ? b : a;
    float f = (s & 2) ? d : c;
    return (s & 4) ? f : e;
}

// ---------------------------------------------------------------------------
// One-time prep: split x into bf16 hi/lo; transpose+split W_in, W_x, W_out
// into [N][K] k-contiguous bf16 hi/lo (B-operand layout for MFMA).
// ---------------------------------------------------------------------------
__global__ __launch_bounds__(256) void prep_w_k(
    const float* __restrict__ x, const float* __restrict__ W_in,
    const float* __restrict__ W_x, const float* __restrict__ W_out,
    unsigned short* __restrict__ x_hi,  unsigned short* __restrict__ x_lo,
    unsigned short* __restrict__ WiT_hi, unsigned short* __restrict__ WiT_lo,
    unsigned short* __restrict__ WxT_hi, unsigned short* __restrict__ WxT_lo,
    unsigned short* __restrict__ WoT_hi, unsigned short* __restrict__ WoT_lo)
{
    int idx = blockIdx.x * 256 + threadIdx.x;
    float v;
    unsigned short *dh, *dl;
    size_t di;
    if (idx < 409600) {
        v = x[idx]; dh = x_hi; dl = x_lo; di = idx;
    } else if (idx < 409600 + 262144) {
        int l = idx - 409600;
        int n = l >> 8, k = l & 255;
        v = W_in[(size_t)k * 1024 + n]; dh = WiT_hi; dl = WiT_lo; di = l;
    } else if (idx < 409600 + 262144 + 73728) {
        int l = idx - (409600 + 262144);
        int n = l >> 9, k = l & 511;
        v = W_x[(size_t)k * 144 + n]; dh = WxT_hi; dl = WxT_lo; di = l;
    } else if (idx < 409600 + 262144 + 73728 + 131072) {
        int l = idx - (409600 + 262144 + 73728);
        int n = l >> 9, k = l & 511;
        v = W_out[(size_t)k * 256 + n]; dh = WoT_hi; dl = WoT_lo; di = l;
    } else return;
    unsigned short h = f2bf(v);
    dh[di] = h;
    dl[di] = f2bf(v - bf2f(h));
}

// ---------------------------------------------------------------------------
// Split-bf16 MFMA GEMM: hi·hi + hi·lo + lo·hi. 64x64 tile, 4 waves of 32x32.
// ---------------------------------------------------------------------------
__global__ __launch_bounds__(256) void gemm_mfma(
    const unsigned short* __restrict__ A_hi, const unsigned short* __restrict__ A_lo,
    const unsigned short* __restrict__ BT_hi, const unsigned short* __restrict__ BT_lo,
    float* __restrict__ C, int M, int N, int K, const float* __restrict__ resid)
{
    __shared__ unsigned short As_hi[64 * 40], As_lo[64 * 40];
    __shared__ unsigned short Bs_hi[64 * 40], Bs_lo[64 * 40];

    const int t    = threadIdx.x;
    const int m0   = blockIdx.y * 64;
    const int n0   = blockIdx.x * 64;
    const int lane = t & 63;
    const int w    = t >> 6;
    const int wm   = (w >> 1) * 32;
    const int wn   = (w & 1) * 32;
    const int fr   = lane & 15;
    const int fq   = lane >> 4;

    const int sr = t >> 2;
    const int sc = (t & 3) * 8;

    f32x4 acc[2][2] = {};

    const size_t a_off = (size_t)(m0 + sr) * K + sc;
    const int    brow  = n0 + sr;
    const size_t b_off = (size_t)brow * K + sc;
    const bool   bok   = brow < N;

    for (int k0 = 0; k0 < K; k0 += 32) {
        int4 ah = *(const int4*)(A_hi + a_off + k0);
        int4 al = *(const int4*)(A_lo + a_off + k0);
        int4 bh = make_int4(0, 0, 0, 0), bl = make_int4(0, 0, 0, 0);
        if (bok) {
            bh = *(const int4*)(BT_hi + b_off + k0);
            bl = *(const int4*)(BT_lo + b_off + k0);
        }
        __syncthreads();
        *(int4*)&As_hi[sr * 40 + sc] = ah;
        *(int4*)&As_lo[sr * 40 + sc] = al;
        *(int4*)&Bs_hi[sr * 40 + sc] = bh;
        *(int4*)&Bs_lo[sr * 40 + sc] = bl;
        __syncthreads();

        bf16x8 a_h[2], a_l[2], b_h[2], b_l[2];
#pragma unroll
        for (int mi = 0; mi < 2; mi++) {
            int row = wm + mi * 16 + fr;
            a_h[mi] = *(const bf16x8*)&As_hi[row * 40 + fq * 8];
            a_l[mi] = *(const bf16x8*)&As_lo[row * 40 + fq * 8];
        }
#pragma unroll
        for (int ni = 0; ni < 2; ni++) {
            int row = wn + ni * 16 + fr;
            b_h[ni] = *(const bf16x8*)&Bs_hi[row * 40 + fq * 8];
            b_l[ni] = *(const bf16x8*)&Bs_lo[row * 40 + fq * 8];
        }
#pragma unroll
        for (int mi = 0; mi < 2; mi++)
#pragma unroll
            for (int ni = 0; ni < 2; ni++) {
                acc[mi][ni] = __builtin_amdgcn_mfma_f32_16x16x32_bf16(a_h[mi], b_h[ni], acc[mi][ni], 0, 0, 0);
                acc[mi][ni] = __builtin_amdgcn_mfma_f32_16x16x32_bf16(a_h[mi], b_l[ni], acc[mi][ni], 0, 0, 0);
                acc[mi][ni] = __builtin_amdgcn_mfma_f32_16x16x32_bf16(a_l[mi], b_h[ni], acc[mi][ni], 0, 0, 0);
            }
    }

#pragma unroll
    for (int mi = 0; mi < 2; mi++)
#pragma unroll
        for (int ni = 0; ni < 2; ni++) {
            int col = n0 + wn + ni * 16 + fr;
            if (col < N) {
#pragma unroll
                for (int reg = 0; reg < 4; reg++) {
                    int row = m0 + wm + mi * 16 + fq * 4 + reg;
                    float v = acc[mi][ni][reg];
                    if (resid) v += resid[(size_t)row * N + col];
                    C[(size_t)row * N + col] = v;
                }
            }
        }
}

// ---------------------------------------------------------------------------
// Depthwise causal conv (width 4) + bias + silu; emits fp32 + split bf16.
// ---------------------------------------------------------------------------
__global__ __launch_bounds__(256) void conv_silu_k(
    const float* __restrict__ xz, const float* __restrict__ conv_w,
    const float* __restrict__ conv_b, float* __restrict__ xm,
    unsigned short* __restrict__ xm_hi, unsigned short* __restrict__ xm_lo)
{
    int idx = blockIdx.x * 256 + threadIdx.x;   // < ROWS*512 = 819200
    int c = idx & 511;
    int r = idx >> 9;
    int l = r % LSEQ;

    float w0 = conv_w[c * 4 + 0];
    float w1 = conv_w[c * 4 + 1];
    float w2 = conv_w[c * 4 + 2];
    float w3 = conv_w[c * 4 + 3];

    const float* base = xz + (size_t)r * 1024 + c;
    float acc = conv_b[c];
    if (l >= 3) acc = fmaf(base[-3 * 1024], w0, acc);
    if (l >= 2) acc = fmaf(base[-2 * 1024], w1, acc);
    if (l >= 1) acc = fmaf(base[-1 * 1024], w2, acc);
    acc = fmaf(base[0], w3, acc);

    float s = siluf(acc);
    xm[idx] = s;
    unsigned short h = f2bf(s);
    xm_hi[idx] = h;
    xm_lo[idx] = f2bf(s - bf2f(h));
}

// ---------------------------------------------------------------------------
// dtq_k (merged with pack_bc): writes
//   dtq[b][d][l] = (dt, dt*u, u, silu(z))  -- l-contiguous float4
//   bcq[b][lblk][n][t][2] = (B, C+phase)   -- done by blockIdx.y==0 blocks
// ---------------------------------------------------------------------------
__global__ __launch_bounds__(256) void dtq_k(
    const float* __restrict__ xp, const float* __restrict__ W_dt,
    const float* __restrict__ b_dt, const float* __restrict__ dmag,
    const float* __restrict__ xm, const float* __restrict__ xz,
    const float* __restrict__ cosp, const float* __restrict__ sinp,
    const float* __restrict__ W_phase,
    float4* __restrict__ dtq, float* __restrict__ bcq)
{
    const int b   = blockIdx.z;
    const int dt0 = blockIdx.y * 64;
    const int lt0 = blockIdx.x * 32;
    const int t   = threadIdx.x;

    __shared__ float Wl[16][64];
    __shared__ float xr[32][17];
    __shared__ float sc[32];
    __shared__ float xmu[32][64];
    __shared__ float xzs[32][64];

#pragma unroll
    for (int e = 0; e < 4; e++) {
        int idx = t + 256 * e;
        int i = idx >> 6, j = idx & 63;
        Wl[i][j] = W_dt[i * 512 + dt0 + j];
    }
#pragma unroll
    for (int e = 0; e < 2; e++) {
        int idx = t + 256 * e;
        int ll = idx >> 4, i = idx & 15;
        int l = lt0 + ll;
        xr[ll][i] = (l < LSEQ) ? xp[((size_t)(b * LSEQ + l)) * 144 + i] : 0.f;
    }
    if (t < 32) {
        int l = lt0 + t;
        float dm = 0.f;
        if (l < LSEQ) {
#pragma unroll
            for (int j = 0; j < 4; j++) dm += dmag[(b * 4 + j) * LSEQ + l];
        }
        sc[t] = 1.f + softplusf(dm * 0.25f);
    }
#pragma unroll
    for (int e = 0; e < 8; e++) {
        int idx = t + 256 * e;
        int ll = idx >> 6, dj = idx & 63;
        int l = lt0 + ll;
        float uu = 0.f, zz = 0.f;
        if (l < LSEQ) {
            uu = xm[((size_t)(b * LSEQ + l)) * 512 + dt0 + dj];
            zz = xz[((size_t)(b * LSEQ + l)) * 1024 + 512 + dt0 + dj];
        }
        xmu[ll][dj] = uu;
        xzs[ll][dj] = zz;
    }
    __syncthreads();

    const int ll = t & 31;
    const int l  = lt0 + ll;
#pragma unroll
    for (int e = 0; e < 8; e++) {
        int dl = (t >> 5) * 8 + e;
        float acc = b_dt[dt0 + dl];
#pragma unroll
        for (int i = 0; i < 16; i++)
            acc = fmaf(xr[ll][i], Wl[i][dl], acc);
        float dtv = softplusf(acc) * sc[ll];
        float uu  = xmu[ll][dl];
        float sz  = siluf(xzs[ll][dl]);
        if (l < LSEQ)
            dtq[((size_t)(b * 512 + dt0 + dl)) * LSEQ + l] =
                make_float4(dtv, dtv * uu, uu, sz);
    }

    // ---- merged pack_bc: only one d-tile (y==0) per (b, l-tile) does it ----
    if (dt0 == 0) {
#pragma unroll
        for (int e = 0; e < 8; e++) {
            int idx = t + 256 * e;             // 0..2047
            int pll = idx >> 6, n = idx & 63;
            int pl  = lt0 + pll;
            if (pl < LSEQ) {
                int r = b * LSEQ + pl;
                float acc = 0.f;
#pragma unroll
                for (int j = 0; j < 4; j++) {
                    float cp = cosp[(b * 4 + j) * LSEQ + pl];
                    float sp = sinp[(b * 4 + j) * LSEQ + pl];
                    acc = fmaf(cp, W_phase[j * 64 + n], acc);
                    acc = fmaf(sp, W_phase[(4 + j) * 64 + n], acc);
                }
                float Bv = xp[(size_t)r * 144 + 16 + n];
                float Cv = xp[(size_t)r * 144 + 80 + n] + acc;
                size_t o = ((((size_t)b * 25 + (pl >> 3)) * 64 + n) * 8 + (pl & 7)) * 2;
                *(float2*)&bcq[o] = make_float2(Bv, Cv);
            }
        }
    }
}

// ---------------------------------------------------------------------------
// Selective scan v5: one wave per (b,d), lane = state n. T=8 steps/chunk,
// ping-pong double buffer (no copies), deferred reduce-scatter butterfly
// (10 cross-lane ops / 8 steps), scalar-arg mux epilogue, coalesced store.
// ---------------------------------------------------------------------------
#define LOAD_CHUNK(BCV, DQV, LB) do {                                          \
    _Pragma("unroll")                                                          \
    for (int i = 0; i < 4; i++)                                                \
        BCV[i] = *(const float4*)(bcb + (size_t)(LB) * 1024 + i * 4);          \
    _Pragma("unroll")                                                          \
    for (int tt = 0; tt < 8; tt++) DQV[tt] = dqp[(LB) * 8 + tt];               \
} while (0)

#define SCAN_CHUNK(BCV, DQV, L0) do {                                          \
    float p[8];                                                                \
    _Pragma("unroll")                                                          \
    for (int tt = 0; tt < 8; tt++) {                                           \
        float Bv = (tt & 1) ? BCV[tt >> 1].z : BCV[tt >> 1].x;                 \
        float Cv = (tt & 1) ? BCV[tt >> 1].w : BCV[tt >> 1].y;                 \
        float e = __expf(DQV[tt].x * A);                                       \
        h = fmaf(e, h, DQV[tt].y * Bv);                                        \
        p[tt] = h * Cv;                                                        \
    }                                                                          \
    float q[4];                                                                \
    _Pragma("unroll")                                                          \
    for (int i = 0; i < 4; i++) {                                              \
        float keep = lo32 ? p[i] : p[i + 4];                                   \
        float send = lo32 ? p[i + 4] : p[i];                                   \
        q[i] = keep + __shfl_xor(send, 32, 64);                                \
    }                                                                          \
    float r2[2];                                                               \
    _Pragma("unroll")                                                          \
    for (int i = 0; i < 2; i++) {                                              \
        float keep = lo16 ? q[i] : q[i + 2];                                   \
        float send = lo16 ? q[i + 2] : q[i];                                   \
        r2[i] = keep + __shfl_xor(send, 16, 64);                               \
    }                                                                          \
    float keep8 = lo8 ? r2[0] : r2[1];                                         \
    float send8 = lo8 ? r2[1] : r2[0];                                         \
    float s = keep8 + __shfl_xor(send8, 8, 64);                                \
    s += __shfl_xor(s, 4, 64);                                                 \
    s += __shfl_xor(s, 2, 64);                                                 \
    s += __shfl_xor(s, 1, 64);                                                 \
    float usel  = mux8s(DQV[0].z, DQV[1].z, DQV[2].z, DQV[3].z,                \
                        DQV[4].z, DQV[5].z, DQV[6].z, DQV[7].z, tsel);         \
    float szsel = mux8s(DQV[0].w, DQV[1].w, DQV[2].w, DQV[3].w,                \
                        DQV[4].w, DQV[5].w, DQV[6].w, DQV[7].w, tsel);         \
    float yv = (s + usel * Dd) * szsel;                                        \
    if (store_lane) yp[(L0) + tsel] = yv;                                      \
} while (0)

__global__ __launch_bounds__(256, 4) void scan_k(
    const float4* __restrict__ dtq, const float* __restrict__ bcq,
    const float* __restrict__ A_log, const float* __restrict__ D_skip,
    float* __restrict__ y2)
{
    int wv0  = blockIdx.x * 4 + (threadIdx.x >> 6);      // 0..4095
    int wv   = __builtin_amdgcn_readfirstlane(wv0);
    int lane = threadIdx.x & 63;
    int b = wv >> 9;
    int d = wv & 511;

    float A  = -__expf(A_log[d * 64 + lane]);
    float Dd = D_skip[d];

    const float4* dqp = dtq + (size_t)(b * 512 + d) * LSEQ;  // indexed as float4[l]
    const float*  bcb = bcq + ((size_t)b * 25 * 64 + lane) * 16;
    float*        yp  = y2  + (size_t)(b * 512 + d) * LSEQ;

    const bool lo32 = (lane & 32) == 0;
    const bool lo16 = (lane & 16) == 0;
    const bool lo8  = (lane & 8)  == 0;
    const bool store_lane = (lane & 7) == 0;
    const int  tsel = lane >> 3;

    float4 bc0[4], dq0[8], bc1[4], dq1[8];
    LOAD_CHUNK(bc0, dq0, 0);

    float h = 0.f;
    for (int it = 0; it < 12; ++it) {        // chunks 0..23 (l = 0..191)
        LOAD_CHUNK(bc1, dq1, 2 * it + 1);
        SCAN_CHUNK(bc0, dq0, 16 * it);
        LOAD_CHUNK(bc0, dq0, 2 * it + 2);    // it=11 loads chunk 24
        SCAN_CHUNK(bc1, dq1, 16 * it + 8);
    }
    SCAN_CHUNK(bc0, dq0, 192);               // chunk 24
}

// ---------------------------------------------------------------------------
// Transpose y2 [b][d][l] -> split bf16 [r=b*200+l][d] for the W_out GEMM.
// ---------------------------------------------------------------------------
__global__ __launch_bounds__(256) void yT_k(
    const float* __restrict__ y2,
    unsigned short* __restrict__ y_hi, unsigned short* __restrict__ y_lo)
{
    __shared__ float tile[64][65];
    const int b   = blockIdx.z;
    const int dt0 = blockIdx.y * 64;
    const int lt0 = blockIdx.x * 64;
    const int t   = threadIdx.x;

#pragma unroll
    for (int e = 0; e < 16; e++) {
        int idx = t + 256 * e;
        int dl = idx >> 6, ll = idx & 63;
        int l = lt0 + ll;
        tile[dl][ll] = (l < LSEQ) ? y2[((size_t)(b * 512 + dt0 + dl)) * LSEQ + l] : 0.f;
    }
    __syncthreads();
#pragma unroll
    for (int e = 0; e < 16; e++) {
        int idx = t + 256 * e;
        int ll = idx >> 6, dl = idx & 63;
        int l = lt0 + ll;
        if (l < LSEQ) {
            float v = tile[dl][ll];
            unsigned short h = f2bf(v);
            size_t o = ((size_t)(b * LSEQ + l)) * 512 + dt0 + dl;
            y_hi[o] = h;
            y_lo[o] = f2bf(v - bf2f(h));
        }
    }
}

// ---------------------------------------------------------------------------
// LayerNorm over last dim (256) + gamma/beta, fp32 out
// ---------------------------------------------------------------------------
__global__ __launch_bounds__(256) void ln_k(
    const float* __restrict__ outp, const float* __restrict__ gamma,
    const float* __restrict__ beta, float* __restrict__ out)
{
    int r = blockIdx.x;
    int t = threadIdx.x;
    float v = outp[(size_t)r * 256 + t];
    float s = v, ss = v * v;
#pragma unroll
    for (int off = 32; off > 0; off >>= 1) {
        s  += __shfl_xor(s,  off, 64);
        ss += __shfl_xor(ss, off, 64);
    }
    __shared__ float red[8];
    int w = t >> 6;
    if ((t & 63) == 0) { red[w] = s; red[4 + w] = ss; }
    __syncthreads();
    s  = red[0] + red[1] + red[2] + red[3];
    ss = red[4] + red[5] + red[6] + red[7];
    float mu  = s * (1.f / 256.f);
    float var = ss * (1.f / 256.f) - mu * mu;
    if (var < 0.f) var = 0.f;
    float inv = rsqrtf(var + 1e-12f);
    float o = (v - mu) * inv * gamma[t] + beta[t];
    out[(size_t)r * 256 + t] = o;
}

// ---------------------------------------------------------------------------
extern "C" void kernel_launch(void* const* d_in, const int* in_sizes, int n_in,
                              void* d_out, int out_size, void* d_ws, size_t ws_size,
                              hipStream_t stream)
{
    const float* x       = (const float*)d_in[0];
    const float* cosp    = (const float*)d_in[1];
    const float* sinp    = (const float*)d_in[2];
    const float* dmag    = (const float*)d_in[3];
    const float* W_in    = (const float*)d_in[4];
    const float* conv_w  = (const float*)d_in[5];
    const float* conv_b  = (const float*)d_in[6];
    const float* W_x     = (const float*)d_in[7];
    const float* W_dt    = (const float*)d_in[8];
    const float* b_dt    = (const float*)d_in[9];
    const float* A_log   = (const float*)d_in[10];
    const float* D_skip  = (const float*)d_in[11];
    const float* W_out   = (const float*)d_in[12];
    const float* gamma   = (const float*)d_in[13];
    const float* beta    = (const float*)d_in[14];
    const float* W_phase = (const float*)d_in[15];
    float* out = (float*)d_out;

    char* ws = (char*)d_ws;
    float*  xz     = (float*)ws;  ws += (size_t)ROWS * 1024 * 4;
    float*  xm     = (float*)ws;  ws += (size_t)ROWS * 512 * 4;
    float*  xp     = (float*)ws;  ws += (size_t)ROWS * 144 * 4;
    float*  bcq    = (float*)ws;  ws += (size_t)ROWS * 128 * 4;
    float4* dtq    = (float4*)ws; ws += (size_t)B_SZ * 512 * LSEQ * 16;
    float*  y2     = (float*)ws;  ws += (size_t)ROWS * 512 * 4;
    float*  outp   = (float*)ws;  ws += (size_t)ROWS * 256 * 4;
    unsigned short* x_hi   = (unsigned short*)ws; ws += (size_t)ROWS * 256 * 2;
    unsigned short* x_lo   = (unsigned short*)ws; ws += (size_t)ROWS * 256 * 2;
    unsigned short* WiT_hi = (unsigned short*)ws; ws += (size_t)1024 * 256 * 2;
    unsigned short* WiT_lo = (unsigned short*)ws; ws += (size_t)1024 * 256 * 2;
    unsigned short* WxT_hi = (unsigned short*)ws; ws += (size_t)144 * 512 * 2;
    unsigned short* WxT_lo = (unsigned short*)ws; ws += (size_t)144 * 512 * 2;
    unsigned short* WoT_hi = (unsigned short*)ws; ws += (size_t)256 * 512 * 2;
    unsigned short* WoT_lo = (unsigned short*)ws; ws += (size_t)256 * 512 * 2;
    unsigned short* xm_hi  = (unsigned short*)ws; ws += (size_t)ROWS * 512 * 2;
    unsigned short* xm_lo  = (unsigned short*)ws; ws += (size_t)ROWS * 512 * 2;
    unsigned short* yf_hi  = (unsigned short*)ws; ws += (size_t)ROWS * 512 * 2;
    unsigned short* yf_lo  = (unsigned short*)ws; ws += (size_t)ROWS * 512 * 2;

    dim3 blk(256);
    prep_w_k   <<<dim3(3424),    blk, 0, stream>>>(x, W_in, W_x, W_out,
                                                   x_hi, x_lo, WiT_hi, WiT_lo,
                                                   WxT_hi, WxT_lo, WoT_hi, WoT_lo);
    gemm_mfma  <<<dim3(16, 25),  blk, 0, stream>>>(x_hi, x_lo, WiT_hi, WiT_lo,
                                                   xz, ROWS, 1024, 256, nullptr);
    conv_silu_k<<<dim3(3200),    blk, 0, stream>>>(xz, conv_w, conv_b, xm, xm_hi, xm_lo);
    gemm_mfma  <<<dim3(3, 25),   blk, 0, stream>>>(xm_hi, xm_lo, WxT_hi, WxT_lo,
                                                   xp, ROWS, 144, 512, nullptr);
    dtq_k      <<<dim3(7, 8, 8), blk, 0, stream>>>(xp, W_dt, b_dt, dmag, xm, xz,
                                                   cosp, sinp, W_phase, dtq, bcq);
    scan_k     <<<dim3(1024),    blk, 0, stream>>>(dtq, bcq, A_log, D_skip, y2);
    yT_k       <<<dim3(4, 8, 8), blk, 0, stream>>>(y2, yf_hi, yf_lo);
    gemm_mfma  <<<dim3(4, 25),   blk, 0, stream>>>(yf_hi, yf_lo, WoT_hi, WoT_lo,
                                                   outp, ROWS, 256, 512, x);
    ln_k       <<<dim3(1600),    blk, 0, stream>>>(outp, gamma, beta, out);
}